// Round 2
// baseline (1248.855 us; speedup 1.0000x reference)
//
#include <hip/hip_runtime.h>
#include <hip/hip_bf16.h>

#define N_ 4
#define C_ 1024
#define D_ 768
#define H_ 12
#define E_ 24
#define M_ 4
#define P_ 552
#define R_ 97
#define HD_ 64
#define D3_ (3*D_)
#define NP_ (N_*P_)

#define SCALE_ 0.036084391824351615f  // 1/sqrt(768)

typedef __attribute__((ext_vector_type(8))) short v8s;
typedef __attribute__((ext_vector_type(4))) float v4f;

__device__ inline ushort f2bf(float x) {
    union { float f; unsigned u; } v; v.f = x;
    unsigned r = (v.u + 0x7FFF + ((v.u >> 16) & 1)) >> 16;
    return (ushort)r;
}

// async global->LDS 16B (direct-to-shared DMA, counts on vmcnt)
__device__ inline void gl_lds16(const ushort* g, ushort* l) {
    __builtin_amdgcn_global_load_lds(
        (const __attribute__((address_space(1))) unsigned int*)(const void*)g,
        (__attribute__((address_space(3))) unsigned int*)(void*)l,
        16, 0, 0);
}

// ---------------- L1: all weight transposes + rels cast + ent_emb/ent_att ----------------
__device__ inline void tcast32(const float* __restrict__ X, ushort* __restrict__ Xt,
                               int K, int N, int yt, int xt, float (*tile)[33], int t) {
    int row = t >> 5, col = t & 31;
    int r0 = yt * 32, c0 = xt * 32;
    #pragma unroll
    for (int i = 0; i < 4; i++) {
        int r = r0 + row + i*8, c = c0 + col;
        tile[row + i*8][col] = (r < K && c < N) ? X[(long)r*N + c] : 0.f;
    }
    __syncthreads();
    #pragma unroll
    for (int i = 0; i < 4; i++) {
        int n = c0 + row + i*8, k = r0 + col;
        if (n < N && k < K) Xt[(long)n*K + k] = f2bf(tile[col][row + i*8]);
    }
}

__global__ __launch_bounds__(256) void k_prep_ent(
        const float* __restrict__ seq, const float* __restrict__ att,
        const int* __restrict__ epos,
        const float* __restrict__ We, const float* __restrict__ Wq,
        const float* __restrict__ Wk, const float* __restrict__ Wv,
        const float* __restrict__ Wc, const float* __restrict__ rels,
        ushort* __restrict__ seqT, ushort* __restrict__ WeT, ushort* __restrict__ W3T,
        ushort* __restrict__ WcT, ushort* __restrict__ relsB,
        float* __restrict__ entEmb, float* __restrict__ entAtt,
        int* __restrict__ bar) {
    __shared__ float tile[32][33];
    int b = blockIdx.x, t = threadIdx.x;
    if (b == 0 && t == 0) *bar = 0;   // reset grid barrier for k_mega (re-done every replay)
    if (b < 6697) {
        // ---- prep part ----
        if (b < 3072) {                    // seqT: 4 batches x (24 x 32) tiles
            int z = b / 768, r = b % 768;
            tcast32(seq + (long)z*C_*D_, seqT + (long)z*D_*C_, C_, D_, r/24, r%24, tile, t);
        } else if (b < 4800) {             // WeT: 24 x 72
            int r = b - 3072;
            tcast32(We, WeT, D3_, D_, r/24, r%24, tile, t);
        } else if (b < 6528) {             // Wq/Wk/Wv: 3 x (24 x 24)
            int r3 = b - 4800;
            int z = r3 / 576, r = r3 % 576;
            const float* X = (z == 0) ? Wq : (z == 1) ? Wk : Wv;
            tcast32(X, W3T + (size_t)z*D_*D_, D_, D_, r/24, r%24, tile, t);
        } else if (b < 6624) {             // WcT: 4 x 24
            int r = b - 6528;
            tcast32(Wc, WcT, D_, R_, r/4, r%4, tile, t);
        } else {                           // rels cast: 73 blocks x 1024 elems
            int base = (b - 6624) * 1024 + t * 4;
            #pragma unroll
            for (int j = 0; j < 4; j++) {
                int i = base + j;
                if (i < R_*D_) relsB[i] = f2bf(rels[i]);
            }
        }
    } else {
        // ---- ent part ----
        int b2 = b - 6697;
        if (b2 < 288) {                    // ent_emb over N*E*D = 288*256 exactly
            int idx = b2*256 + t;
            int d  = idx % D_;
            int ne = idx / D_;
            int e  = ne % E_;
            int n  = ne / E_;
            const int* pp = epos + (n*E_ + e)*M_;
            float v[M_];
            float mx = -1e30f;
            #pragma unroll
            for (int m = 0; m < M_; m++) {
                int pos = pp[m] + 1;  // OFFSET
                v[m] = seq[((long)n*C_ + pos)*D_ + d];
                mx = fmaxf(mx, v[m]);
            }
            float s = 0.f;
            #pragma unroll
            for (int m = 0; m < M_; m++) s += expf(v[m] - mx);
            entEmb[idx] = mx + logf(s);
        } else {                           // ent_att over N*E*H*C = 4608*256 exactly
            long idx = (long)(b2 - 288)*256 + t;
            int c = idx % C_;
            long r = idx / C_;
            int h = r % H_; r /= H_;
            int e = r % E_;
            int n = r / E_;
            const int* pp = epos + (n*E_ + e)*M_;
            float s = 0.f;
            #pragma unroll
            for (int m = 0; m < M_; m++) {
                int pos = pp[m] + 1;
                s += att[(((long)n*H_ + h)*C_ + pos)*C_ + c];
            }
            entAtt[idx] = s * (1.0f / M_);
        }
    }
}

// ---------------- shared-memory union for the mega kernel ----------------
union __align__(16) SM {
    struct { ushort As[4*4096]; ushort Bs[4*4096]; } g;                       // 65536 B
    struct { ushort U[128*128]; ushort Vs[64*128];
             float rowm[2][128]; float rowl[2][128]; } a1;                     // 51200 B
    struct { ushort Qs[128*64]; ushort KV[128*64]; ushort Ps[128*128];
             float rowm[2][128]; float rowl[2][128];
             float mrun[128]; float lrun[128]; float alphaS[128]; } a2;        // 69120 B
    struct { float red[256]; } r;
};

// ---------------- device-scope grid barrier (all blocks co-resident) ----------------
// Monotonic: barrier #it waits until counter reaches 256*it. Counter zeroed by k_prep_ent.
__device__ __forceinline__ void gbar(int* bar, int it) {
    __threadfence();                 // release: all our global stores visible device-wide
    __syncthreads();                 // whole block done + fenced
    if (threadIdx.x == 0) {
        __hip_atomic_fetch_add(bar, 1, __ATOMIC_ACQ_REL, __HIP_MEMORY_SCOPE_AGENT);
        while (__hip_atomic_load(bar, __ATOMIC_ACQUIRE, __HIP_MEMORY_SCOPE_AGENT) < 256*it) {
            __builtin_amdgcn_s_sleep(2);
        }
    }
    __syncthreads();
    __threadfence();                 // acquire: invalidate stale cache lines for all waves
}

// ---------------- phase bodies (byte-identical logic to round-1 kernels) ----------------

__device__ __forceinline__ void gath_one(int b,
        const float* __restrict__ entEmb, const float* __restrict__ entAtt,
        const int* __restrict__ hts,
        ushort* __restrict__ bcat, ushort* __restrict__ bhtAtt, float* red) {
    int t = threadIdx.x;
    if (b < 6624) {                    // gather over N*P*D = 6624*256 exactly
        int idx = b*256 + t;
        int d  = idx % D_;
        int np = idx / D_;
        int p  = np % P_;
        int n  = np / P_;
        int hi = hts[(n*P_ + p)*2 + 0];
        int ti = hts[(n*P_ + p)*2 + 1];
        bcat[(long)np*D3_ + d]       = f2bf(entEmb[((long)n*E_ + hi)*D_ + d]);
        bcat[(long)np*D3_ + D_ + d]  = f2bf(entEmb[((long)n*E_ + ti)*D_ + d]);
    } else {                           // ht_att: 2208 virtual blocks
        int np = b - 6624;
        int p = np % P_, n = np / P_;
        int hi = hts[(n*P_ + p)*2 + 0];
        int ti = hts[(n*P_ + p)*2 + 1];
        const float* ha = entAtt + ((long)n*E_ + hi)*H_*C_;
        const float* ta = entAtt + ((long)n*E_ + ti)*H_*C_;
        float vals[C_/256];
        float lsum = 0.f;
        #pragma unroll
        for (int i = 0; i < C_/256; i++) {
            int c = t + i*256;
            float s = 0.f;
            #pragma unroll
            for (int h = 0; h < H_; h++) s += ha[h*C_ + c] * ta[h*C_ + c];
            s *= (1.0f / H_);
            vals[i] = s;
            lsum += s;
        }
        red[t] = lsum; __syncthreads();
        for (int s1 = 128; s1; s1 >>= 1) { if (t < s1) red[t] += red[t+s1]; __syncthreads(); }
        float inv = 1.0f / (red[0] + 1e-5f);
        #pragma unroll
        for (int i = 0; i < C_/256; i++)
            bhtAtt[(long)np*C_ + t + i*256] = f2bf(vals[i] * inv);
    }
}

// bf16 MFMA GEMM core: distance-2 pipeline, 4 LDS buffers, counted vmcnt (round-1 proven)
__device__ __forceinline__ void gemm_core(
        int bx, int by,
        const ushort* __restrict__ A, const ushort* __restrict__ Bt,
        const float* __restrict__ bias, float* __restrict__ Cf, ushort* __restrict__ Cb,
        long cfo, long cbo,
        int M, int N, int Npad, int K,
        int lda, int ldb, int ldcf, int ldcb,
        int act, int biasM,
        ushort* __restrict__ As, ushort* __restrict__ Bs) {
    int t = threadIdx.x;
    int m0 = by * 128, n0 = bx * 128;
    int lr = t >> 2;            // 0..63
    int lc = (t & 3) * 8;       // 0,8,16,24
    int wv = t >> 6, lane = t & 63;
    int quad = lane >> 4, lm = lane & 15;
    int wm = (wv >> 1) * 64, wn = (wv & 1) * 64;

    const ushort* pA0 = A + (long)min(m0 + lr,      M-1)*lda + lc;
    const ushort* pA1 = A + (long)min(m0 + lr + 64, M-1)*lda + lc;
    const ushort* pB0 = Bt + (long)min(n0 + lr,      N-1)*ldb + lc;
    const ushort* pB1 = Bt + (long)min(n0 + lr + 64, N-1)*ldb + lc;

    v4f acc[4][4];
    #pragma unroll
    for (int i = 0; i < 4; i++)
        #pragma unroll
        for (int j = 0; j < 4; j++)
            acc[i][j] = (v4f){0.f, 0.f, 0.f, 0.f};

    int nIter = K >> 5;
    gl_lds16(pA0, As + t*8);
    gl_lds16(pA1, As + 2048 + t*8);
    gl_lds16(pB0, Bs + t*8);
    gl_lds16(pB1, Bs + 2048 + t*8);
    if (nIter > 1) {
        gl_lds16(pA0 + 32, As + 4096 + t*8);
        gl_lds16(pA1 + 32, As + 4096 + 2048 + t*8);
        gl_lds16(pB0 + 32, Bs + 4096 + t*8);
        gl_lds16(pB1 + 32, Bs + 4096 + 2048 + t*8);
    }

    for (int it = 0; it < nIter; ++it) {
        int cur = (it & 3) * 4096;
        if (it + 2 < nIter) {
            asm volatile("s_waitcnt vmcnt(4)\n\ts_barrier" ::: "memory");
            int nb = ((it + 2) & 3) * 4096;
            int k2 = (it + 2) << 5;
            gl_lds16(pA0 + k2, As + nb + t*8);
            gl_lds16(pA1 + k2, As + nb + 2048 + t*8);
            gl_lds16(pB0 + k2, Bs + nb + t*8);
            gl_lds16(pB1 + k2, Bs + nb + 2048 + t*8);
        } else {
            asm volatile("s_waitcnt vmcnt(0)\n\ts_barrier" ::: "memory");
        }
        v8s a[4], b[4];
        #pragma unroll
        for (int i = 0; i < 4; i++)
            a[i] = *(const v8s*)(As + cur + (wm + i*16 + lm)*32 + quad*8);
        #pragma unroll
        for (int j = 0; j < 4; j++)
            b[j] = *(const v8s*)(Bs + cur + (wn + j*16 + lm)*32 + quad*8);
        #pragma unroll
        for (int i = 0; i < 4; i++)
            #pragma unroll
            for (int j = 0; j < 4; j++)
                acc[i][j] = __builtin_amdgcn_mfma_f32_16x16x32_bf16(a[i], b[j], acc[i][j], 0, 0, 0);
    }

    #pragma unroll
    for (int j = 0; j < 4; j++) {
        int gn = n0 + wn + j*16 + lm;
        if (gn >= Npad) continue;
        bool vld = gn < N;
        float bvn = (bias && !biasM && vld) ? bias[gn] : 0.f;
        #pragma unroll
        for (int i = 0; i < 4; i++) {
            #pragma unroll
            for (int reg = 0; reg < 4; reg++) {
                int gm = m0 + wm + i*16 + quad*4 + reg;
                if (gm >= M) continue;
                float v = 0.f;
                if (vld) {
                    v = acc[i][j][reg] + bvn;
                    if (bias && biasM) v += bias[gm];
                    if (act == 1) v = tanhf(v);
                }
                if (Cf) Cf[cfo + (long)gm*ldcf + gn] = v;
                if (Cb) Cb[cbo + (long)gm*ldcb + gn] = f2bf(v);
            }
        }
    }
}

__device__ __forceinline__ void attn1_one(int mt, int h,
        const ushort* __restrict__ qb, const ushort* __restrict__ kb,
        const ushort* __restrict__ vT, ushort* __restrict__ o1b, SM& sm) {
    int m0 = mt * 128;
    ushort* Qs = sm.a1.U;
    ushort* Ks = sm.a1.U + 128*64;
    ushort* Ps = sm.a1.U;
    ushort* Vs = sm.a1.Vs;
    auto& rowm = sm.a1.rowm;
    auto& rowl = sm.a1.rowl;
    int t = threadIdx.x;
    const uint4 z4 = {0u,0u,0u,0u};
    #pragma unroll
    for (int i = 0; i < 4; i++) {
        int id = t + i*256;
        int row = id >> 3, c8 = (id & 7) * 8;
        int np = m0 + row;
        uint4 qv = z4;
        if (np < NP_) qv = *(const uint4*)(qb + (long)np*D_ + h*HD_ + c8);
        *(uint4*)(Qs + row*64 + c8) = qv;
        uint4 kv = z4;
        if (row < R_) kv = *(const uint4*)(kb + (long)row*D_ + h*HD_ + c8);
        *(uint4*)(Ks + row*64 + c8) = kv;
    }
    #pragma unroll
    for (int i = 0; i < 4; i++) {
        int id = t + i*256;
        int e = id >> 4, c8 = (id & 15) * 8;
        *(uint4*)(Vs + e*128 + c8) = *(const uint4*)(vT + ((long)h*HD_ + e)*128 + c8);
    }
    __syncthreads();
    int wv = t >> 6, lane = t & 63;
    int quad = lane >> 4, lm = lane & 15;
    int wm = (wv >> 1) * 64, wn = (wv & 1) * 64;
    int side = wv & 1;

    v4f acc[4][4];
    #pragma unroll
    for (int i = 0; i < 4; i++)
        #pragma unroll
        for (int j = 0; j < 4; j++)
            acc[i][j] = (v4f){0.f,0.f,0.f,0.f};
    #pragma unroll
    for (int k0 = 0; k0 < 64; k0 += 32) {
        v8s a[4], b[4];
        #pragma unroll
        for (int i = 0; i < 4; i++) a[i] = *(const v8s*)(Qs + (wm + i*16 + lm)*64 + k0 + quad*8);
        #pragma unroll
        for (int j = 0; j < 4; j++) b[j] = *(const v8s*)(Ks + (wn + j*16 + lm)*64 + k0 + quad*8);
        #pragma unroll
        for (int i = 0; i < 4; i++)
            #pragma unroll
            for (int j = 0; j < 4; j++)
                acc[i][j] = __builtin_amdgcn_mfma_f32_16x16x32_bf16(a[i], b[j], acc[i][j], 0, 0, 0);
    }
    #pragma unroll
    for (int j = 0; j < 4; j++) {
        int col = wn + j*16 + lm;
        bool ok = col < R_;
        #pragma unroll
        for (int i = 0; i < 4; i++)
            #pragma unroll
            for (int reg = 0; reg < 4; reg++)
                acc[i][j][reg] = ok ? acc[i][j][reg]*SCALE_ : -1e30f;
    }
    #pragma unroll
    for (int i = 0; i < 4; i++)
        #pragma unroll
        for (int reg = 0; reg < 4; reg++) {
            float m = fmaxf(fmaxf(acc[i][0][reg], acc[i][1][reg]),
                            fmaxf(acc[i][2][reg], acc[i][3][reg]));
            #pragma unroll
            for (int o = 1; o < 16; o <<= 1) m = fmaxf(m, __shfl_xor(m, o));
            if (lm == 0) rowm[side][wm + i*16 + quad*4 + reg] = m;
        }
    __syncthreads();
    #pragma unroll
    for (int i = 0; i < 4; i++)
        #pragma unroll
        for (int reg = 0; reg < 4; reg++) {
            int r = wm + i*16 + quad*4 + reg;
            float m = fmaxf(rowm[0][r], rowm[1][r]);
            float s = 0.f;
            #pragma unroll
            for (int j = 0; j < 4; j++) {
                float e = expf(acc[i][j][reg] - m);
                acc[i][j][reg] = e;
                s += e;
            }
            #pragma unroll
            for (int o = 1; o < 16; o <<= 1) s += __shfl_xor(s, o);
            if (lm == 0) rowl[side][r] = s;
        }
    __syncthreads();
    #pragma unroll
    for (int i = 0; i < 4; i++)
        #pragma unroll
        for (int reg = 0; reg < 4; reg++) {
            int r = wm + i*16 + quad*4 + reg;
            float inv = 1.0f / (rowl[0][r] + rowl[1][r]);
            #pragma unroll
            for (int j = 0; j < 4; j++)
                Ps[r*128 + wn + j*16 + lm] = f2bf(acc[i][j][reg] * inv);
        }
    __syncthreads();
    v4f acc2[2][4];
    #pragma unroll
    for (int i = 0; i < 2; i++)
        #pragma unroll
        for (int j = 0; j < 4; j++)
            acc2[i][j] = (v4f){0.f,0.f,0.f,0.f};
    int wm2 = wv * 32;
    #pragma unroll
    for (int k0 = 0; k0 < 128; k0 += 32) {
        v8s a2[2], b2[4];
        #pragma unroll
        for (int i = 0; i < 2; i++) a2[i] = *(const v8s*)(Ps + (wm2 + i*16 + lm)*128 + k0 + quad*8);
        #pragma unroll
        for (int j = 0; j < 4; j++) b2[j] = *(const v8s*)(Vs + (j*16 + lm)*128 + k0 + quad*8);
        #pragma unroll
        for (int i = 0; i < 2; i++)
            #pragma unroll
            for (int j = 0; j < 4; j++)
                acc2[i][j] = __builtin_amdgcn_mfma_f32_16x16x32_bf16(a2[i], b2[j], acc2[i][j], 0, 0, 0);
    }
    #pragma unroll
    for (int i = 0; i < 2; i++)
        #pragma unroll
        for (int j = 0; j < 4; j++)
            #pragma unroll
            for (int reg = 0; reg < 4; reg++) {
                int row = m0 + wm2 + i*16 + quad*4 + reg;
                if (row >= NP_) continue;
                o1b[(long)row*D_ + h*HD_ + j*16 + lm] = f2bf(acc2[i][j][reg]);
            }
}

__device__ __forceinline__ void attn2_one(int qt, int zz,
        const ushort* __restrict__ o1b, float* __restrict__ o2, SM& sm) {
    int n = zz / H_, h = zz % H_;
    int q0 = qt * 128;
    ushort* Qs = sm.a2.Qs;
    ushort* KV = sm.a2.KV;
    ushort* Ps = sm.a2.Ps;
    auto& rowm = sm.a2.rowm;
    auto& rowl = sm.a2.rowl;
    float* mrun = sm.a2.mrun;
    float* lrun = sm.a2.lrun;
    float* alphaS = sm.a2.alphaS;
    int t = threadIdx.x;
    const ushort* base = o1b + (long)n*P_*D_ + h*HD_;
    const uint4 z4 = {0u,0u,0u,0u};
    #pragma unroll
    for (int i = 0; i < 4; i++) {
        int id = t + i*256;
        int row = id >> 3, c8 = (id & 7) * 8;
        int q = q0 + row;
        uint4 v = z4;
        if (q < P_) v = *(const uint4*)(base + (long)q*D_ + c8);
        *(uint4*)(Qs + row*64 + c8) = v;
    }
    if (t < 128) { mrun[t] = -1e30f; lrun[t] = 0.f; }
    __syncthreads();
    int wv = t >> 6, lane = t & 63;
    int quad = lane >> 4, lm = lane & 15;
    int wm = (wv >> 1) * 64, wn = (wv & 1) * 64;
    int side = wv & 1;
    int wm2 = wv * 32;
    v4f acc2[2][4];
    #pragma unroll
    for (int i = 0; i < 2; i++)
        #pragma unroll
        for (int j = 0; j < 4; j++)
            acc2[i][j] = (v4f){0.f,0.f,0.f,0.f};

    for (int c = 0; c < 5; c++) {
        #pragma unroll
        for (int i = 0; i < 4; i++) {
            int id = t + i*256;
            int row = id >> 3, c8 = (id & 7) * 8;
            int q = c*128 + row;
            uint4 v = z4;
            if (q < P_) v = *(const uint4*)(base + (long)q*D_ + c8);
            *(uint4*)(KV + row*64 + c8) = v;
        }
        __syncthreads();
        v4f acc[4][4];
        #pragma unroll
        for (int i = 0; i < 4; i++)
            #pragma unroll
            for (int j = 0; j < 4; j++)
                acc[i][j] = (v4f){0.f,0.f,0.f,0.f};
        #pragma unroll
        for (int k0 = 0; k0 < 64; k0 += 32) {
            v8s a[4], b[4];
            #pragma unroll
            for (int i = 0; i < 4; i++) a[i] = *(const v8s*)(Qs + (wm + i*16 + lm)*64 + k0 + quad*8);
            #pragma unroll
            for (int j = 0; j < 4; j++) b[j] = *(const v8s*)(KV + (wn + j*16 + lm)*64 + k0 + quad*8);
            #pragma unroll
            for (int i = 0; i < 4; i++)
                #pragma unroll
                for (int j = 0; j < 4; j++)
                    acc[i][j] = __builtin_amdgcn_mfma_f32_16x16x32_bf16(a[i], b[j], acc[i][j], 0, 0, 0);
        }
        #pragma unroll
        for (int j = 0; j < 4; j++) {
            int col = c*128 + wn + j*16 + lm;
            bool ok = col < P_;
            #pragma unroll
            for (int i = 0; i < 4; i++)
                #pragma unroll
                for (int reg = 0; reg < 4; reg++)
                    acc[i][j][reg] = ok ? acc[i][j][reg]*SCALE_ : -1e30f;
        }
        #pragma unroll
        for (int i = 0; i < 4; i++)
            #pragma unroll
            for (int reg = 0; reg < 4; reg++) {
                float m = fmaxf(fmaxf(acc[i][0][reg], acc[i][1][reg]),
                                fmaxf(acc[i][2][reg], acc[i][3][reg]));
                #pragma unroll
                for (int o = 1; o < 16; o <<= 1) m = fmaxf(m, __shfl_xor(m, o));
                if (lm == 0) rowm[side][wm + i*16 + quad*4 + reg] = m;
            }
        __syncthreads();
        #pragma unroll
        for (int i = 0; i < 4; i++)
            #pragma unroll
            for (int reg = 0; reg < 4; reg++) {
                int r = wm + i*16 + quad*4 + reg;
                float mc = fmaxf(rowm[0][r], rowm[1][r]);
                float mn = fmaxf(mrun[r], mc);
                float s = 0.f;
                #pragma unroll
                for (int j = 0; j < 4; j++) {
                    float e = expf(acc[i][j][reg] - mn);
                    acc[i][j][reg] = e;
                    s += e;
                }
                #pragma unroll
                for (int o = 1; o < 16; o <<= 1) s += __shfl_xor(s, o);
                if (lm == 0) rowl[side][r] = s;
            }
        __syncthreads();
        if (t < 128) {
            float mo = mrun[t];
            float mc = fmaxf(rowm[0][t], rowm[1][t]);
            float mn = fmaxf(mo, mc);
            float al = expf(mo - mn);
            lrun[t] = lrun[t]*al + rowl[0][t] + rowl[1][t];
            mrun[t] = mn;
            alphaS[t] = al;
        }
        // stage V^T for this chunk via LDS transpose
        #pragma unroll
        for (int i = 0; i < 4; i++) {
            int id = t + i*256;
            int q = id & 127, e0 = (id >> 7) * 8;
            int gq = c*128 + q;
            uint4 v = z4;
            if (gq < P_) v = *(const uint4*)(base + (long)gq*D_ + e0);
            const ushort* pv = (const ushort*)&v;
            #pragma unroll
            for (int j = 0; j < 8; j++) KV[(e0+j)*128 + q] = pv[j];
        }
        #pragma unroll
        for (int i = 0; i < 4; i++)
            #pragma unroll
            for (int reg = 0; reg < 4; reg++) {
                int r = wm + i*16 + quad*4 + reg;
                #pragma unroll
                for (int j = 0; j < 4; j++)
                    Ps[r*128 + wn + j*16 + lm] = f2bf(acc[i][j][reg]);
            }
        __syncthreads();
        #pragma unroll
        for (int i = 0; i < 2; i++) {
            #pragma unroll
            for (int reg = 0; reg < 4; reg++) {
                float al = alphaS[wm2 + i*16 + quad*4 + reg];
                #pragma unroll
                for (int j = 0; j < 4; j++)
                    acc2[i][j][reg] *= al;
            }
        }
        #pragma unroll
        for (int k0 = 0; k0 < 128; k0 += 32) {
            v8s a2[2], b2[4];
            #pragma unroll
            for (int i = 0; i < 2; i++) a2[i] = *(const v8s*)(Ps + (wm2 + i*16 + lm)*128 + k0 + quad*8);
            #pragma unroll
            for (int j = 0; j < 4; j++) b2[j] = *(const v8s*)(KV + (j*16 + lm)*128 + k0 + quad*8);
            #pragma unroll
            for (int i = 0; i < 2; i++)
                #pragma unroll
                for (int j = 0; j < 4; j++)
                    acc2[i][j] = __builtin_amdgcn_mfma_f32_16x16x32_bf16(a2[i], b2[j], acc2[i][j], 0, 0, 0);
        }
        __syncthreads();
    }
    #pragma unroll
    for (int i = 0; i < 2; i++)
        #pragma unroll
        for (int j = 0; j < 4; j++)
            #pragma unroll
            for (int reg = 0; reg < 4; reg++) {
                int row = wm2 + i*16 + quad*4 + reg;
                int q = q0 + row;
                if (q >= P_) continue;
                float l = lrun[row];
                o2[((long)n*P_ + q)*D_ + h*HD_ + j*16 + lm] = acc2[i][j][reg] / l;
            }
}

__device__ __forceinline__ void ln_one(int np,
        const float* __restrict__ htr, const float* __restrict__ o2,
        const float* __restrict__ g, const float* __restrict__ b,
        ushort* __restrict__ bx, float* red) {
    int t = threadIdx.x;
    float v[D_/256];
    float s = 0.f;
    #pragma unroll
    for (int i = 0; i < D_/256; i++) {
        int d = t + i*256;
        float val = htr[(long)np*D_ + d] + tanhf(o2[(long)np*D_ + d]);
        v[i] = val; s += val;
    }
    red[t] = s; __syncthreads();
    for (int s1 = 128; s1; s1 >>= 1) { if (t < s1) red[t] += red[t+s1]; __syncthreads(); }
    float mu = red[0] * (1.0f/D_);
    __syncthreads();
    float s2 = 0.f;
    #pragma unroll
    for (int i = 0; i < D_/256; i++) { float dx = v[i]-mu; s2 += dx*dx; }
    red[t] = s2; __syncthreads();
    for (int s1 = 128; s1; s1 >>= 1) { if (t < s1) red[t] += red[t+s1]; __syncthreads(); }
    float inv = rsqrtf(red[0]*(1.0f/D_) + 1e-5f);
    #pragma unroll
    for (int i = 0; i < D_/256; i++) {
        int d = t + i*256;
        bx[(long)np*D_ + d] = f2bf((v[i]-mu)*inv*g[d] + b[d]);
    }
}

// ---------------- the persistent mega kernel: 8 phases, 7 grid barriers ----------------
struct Args {
    const float *be, *bq, *bk, *bv, *ln_g, *ln_b, *bc;
    const int *hts;
    float *out;
    float *entEmb, *entAtt, *htr, *o2;
    ushort *bhtAtt, *bcat, *seqT, *WeT, *WqT, *WkT, *WvT, *WcT, *relsB;
    ushort *bhtr, *bqb, *bkb, *vT, *o1b, *bxb;
    int *bar;
};

__global__ __launch_bounds__(256, 1) void k_mega(Args A) {
    __shared__ SM sm;
    int bid = blockIdx.x;

    // P1: gather + ht_att (8832 virtual blocks, grid-stride)
    for (int vb = bid; vb < 8832; vb += 256) {
        gath_one(vb, A.entEmb, A.entAtt, A.hts, A.bcat, A.bhtAtt, sm.r.red);
        __syncthreads();
    }
    gbar(A.bar, 1);

    // P2: rs = batched bhtAtt(n) @ seqT(n)^T -> bcat[:, 2D:3D]   (120 blocks)
    if (bid < 120) {
        int x = bid % 6, r = bid / 6, y = r % 5, z = r / 5;
        gemm_core(x, y, A.bhtAtt + (long)z*P_*C_, A.seqT + (long)z*D_*C_,
                  nullptr, nullptr, A.bcat + 2*D_,
                  0, (long)z*P_*D3_,
                  P_, D_, D_, C_, C_, C_, 0, D3_, 0, 0, sm.g.As, sm.g.Bs);
    }
    gbar(A.bar, 2);

    // P3: htr = tanh(bcat @ WeT^T + be)   (108 blocks)
    if (bid < 108) {
        int x = bid % 6, y = bid / 6;
        gemm_core(x, y, A.bcat, A.WeT, A.be, A.htr, A.bhtr, 0, 0,
                  NP_, D_, D_, D3_, D3_, D3_, D_, D_, 1, 0, sm.g.As, sm.g.Bs);
    }
    gbar(A.bar, 3);

    // P4: q/k/v projections   (150 blocks)
    if (bid < 150) {
        int x = bid % 6, y = bid / 6;
        if (y < 18)
            gemm_core(x, y, A.bhtr, A.WqT, A.bq, nullptr, A.bqb, 0, 0,
                      NP_, D_, D_, D_, D_, D_, 0, D_, 0, 0, sm.g.As, sm.g.Bs);
        else if (y == 18)
            gemm_core(x, 0, A.relsB, A.WkT, A.bk, nullptr, A.bkb, 0, 0,
                      R_, D_, D_, D_, D_, D_, 0, D_, 0, 0, sm.g.As, sm.g.Bs);
        else if (x == 0)
            gemm_core(0, y - 19, A.WvT, A.relsB, A.bv, nullptr, A.vT, 0, 0,
                      D_, R_, 128, D_, D_, D_, 0, 128, 0, 1, sm.g.As, sm.g.Bs);
    }
    gbar(A.bar, 4);

    // P5: fused attn1   (216 blocks)
    if (bid < 216) attn1_one(bid % 18, bid / 18, A.bqb, A.bkb, A.vT, A.o1b, sm);
    gbar(A.bar, 5);

    // P6: fused attn2 (flash)   (240 blocks)
    if (bid < 240) attn2_one(bid % 5, bid / 5, A.o1b, A.o2, sm);
    gbar(A.bar, 6);

    // P7: LN (2208 rows, grid-stride)
    for (int np = bid; np < NP_; np += 256) {
        ln_one(np, A.htr, A.o2, A.ln_g, A.ln_b, A.bxb, sm.r.red);
        __syncthreads();
    }
    gbar(A.bar, 7);

    // P8: logits = bxb @ WcT^T + bc   (18 blocks)
    if (bid < 18)
        gemm_core(0, bid, A.bxb, A.WcT, A.bc, A.out, nullptr, 0, 0,
                  NP_, R_, R_, D_, D_, D_, R_, 0, 0, 0, sm.g.As, sm.g.Bs);
}

extern "C" void kernel_launch(void* const* d_in, const int* in_sizes, int n_in,
                              void* d_out, int out_size, void* d_ws, size_t ws_size,
                              hipStream_t stream) {
    const float* seq   = (const float*)d_in[0];
    const float* att   = (const float*)d_in[1];
    const int*   epos  = (const int*)d_in[2];
    const int*   hts   = (const int*)d_in[3];
    const float* rels  = (const float*)d_in[4];
    const float* We    = (const float*)d_in[5];
    const float* be    = (const float*)d_in[6];
    const float* Wq    = (const float*)d_in[7];
    const float* bq    = (const float*)d_in[8];
    const float* Wk    = (const float*)d_in[9];
    const float* bk    = (const float*)d_in[10];
    const float* Wv    = (const float*)d_in[11];
    const float* bv    = (const float*)d_in[12];
    const float* ln_g  = (const float*)d_in[13];
    const float* ln_b  = (const float*)d_in[14];
    const float* Wc    = (const float*)d_in[15];
    const float* bc    = (const float*)d_in[16];
    float* out = (float*)d_out;
    float* w = (float*)d_ws;

    // ---- f32 workspace ----
    float* entEmb  = w;
    float* entAtt  = entEmb  + (size_t)N_*E_*D_;
    float* htr     = entAtt  + (size_t)N_*E_*H_*C_;
    float* o2      = htr     + (size_t)NP_*D_;
    // ---- bf16 workspace ----
    ushort* bhtAtt = (ushort*)(o2 + (size_t)NP_*D_);
    ushort* bcat   = bhtAtt + (size_t)NP_*C_;
    ushort* seqT   = bcat  + (size_t)NP_*D3_;
    ushort* WeT    = seqT  + (size_t)N_*D_*C_;
    ushort* WqT    = WeT   + (size_t)D_*D3_;
    ushort* WkT    = WqT   + (size_t)D_*D_;
    ushort* WvT    = WkT   + (size_t)D_*D_;
    ushort* WcT    = WvT   + (size_t)D_*D_;
    ushort* relsB  = WcT   + (size_t)D_*R_;
    ushort* bhtr   = relsB + (size_t)R_*D_;
    ushort* bqb    = bhtr  + (size_t)NP_*D_;
    ushort* bkb    = bqb   + (size_t)NP_*D_;
    ushort* vT     = bkb   + (size_t)R_*D_;
    ushort* o1b    = vT    + (size_t)D_*128;
    ushort* bxb    = o1b   + (size_t)NP_*D_;
    int*    bar    = (int*)(bxb + (size_t)NP_*D_);

    // L1: prep (transposes/casts) + ent (logsumexp/att-mean) + barrier reset
    k_prep_ent<<<11593, 256, 0, stream>>>(seq, att, epos, We, Wq, Wk, Wv, Wc, rels,
                                          seqT, WeT, WqT, WcT, relsB,
                                          entEmb, entAtt, bar);

    // L2: everything else as one persistent kernel
    Args Aa;
    Aa.be = be; Aa.bq = bq; Aa.bk = bk; Aa.bv = bv;
    Aa.ln_g = ln_g; Aa.ln_b = ln_b; Aa.bc = bc;
    Aa.hts = hts; Aa.out = out;
    Aa.entEmb = entEmb; Aa.entAtt = entAtt; Aa.htr = htr; Aa.o2 = o2;
    Aa.bhtAtt = bhtAtt; Aa.bcat = bcat; Aa.seqT = seqT; Aa.WeT = WeT;
    Aa.WqT = WqT; Aa.WkT = WkT; Aa.WvT = WvT; Aa.WcT = WcT; Aa.relsB = relsB;
    Aa.bhtr = bhtr; Aa.bqb = bqb; Aa.bkb = bkb; Aa.vT = vT; Aa.o1b = o1b; Aa.bxb = bxb;
    Aa.bar = bar;
    k_mega<<<256, 256, 0, stream>>>(Aa);
}

// Round 4
// 536.443 us; speedup vs baseline: 2.3280x; 2.3280x over previous
//
#include <hip/hip_runtime.h>
#include <hip/hip_bf16.h>

#define N_ 4
#define C_ 1024
#define D_ 768
#define H_ 12
#define E_ 24
#define M_ 4
#define P_ 552
#define R_ 97
#define HD_ 64
#define D3_ (3*D_)
#define NP_ (N_*P_)

#define SCALE_ 0.036084391824351615f  // 1/sqrt(768)

typedef __attribute__((ext_vector_type(8))) short v8s;
typedef __attribute__((ext_vector_type(4))) float v4f;

__device__ inline ushort f2bf(float x) {
    union { float f; unsigned u; } v; v.f = x;
    unsigned r = (v.u + 0x7FFF + ((v.u >> 16) & 1)) >> 16;
    return (ushort)r;
}

// async global->LDS 16B (direct-to-shared DMA, counts on vmcnt)
__device__ inline void gl_lds16(const ushort* g, ushort* l) {
    __builtin_amdgcn_global_load_lds(
        (const __attribute__((address_space(1))) unsigned int*)(const void*)g,
        (__attribute__((address_space(3))) unsigned int*)(void*)l,
        16, 0, 0);
}

// ---------------- L1: weight transposes + seq/rels casts + ent_emb/ent_att ----------------
__device__ inline void tcast32(const float* __restrict__ X, ushort* __restrict__ Xt,
                               int K, int N, int yt, int xt, float (*tile)[33], int t) {
    int row = t >> 5, col = t & 31;
    int r0 = yt * 32, c0 = xt * 32;
    #pragma unroll
    for (int i = 0; i < 4; i++) {
        int r = r0 + row + i*8, c = c0 + col;
        tile[row + i*8][col] = (r < K && c < N) ? X[(long)r*N + c] : 0.f;
    }
    __syncthreads();
    #pragma unroll
    for (int i = 0; i < 4; i++) {
        int n = c0 + row + i*8, k = r0 + col;
        if (n < N && k < K) Xt[(long)n*K + k] = f2bf(tile[col][row + i*8]);
    }
}

__global__ __launch_bounds__(256) void k_prep_ent(
        const float* __restrict__ seq, const float* __restrict__ att,
        const int* __restrict__ epos,
        const float* __restrict__ We, const float* __restrict__ Wq,
        const float* __restrict__ Wk, const float* __restrict__ Wv,
        const float* __restrict__ Wc, const float* __restrict__ rels,
        ushort* __restrict__ seqB, ushort* __restrict__ WeT, ushort* __restrict__ W3T,
        ushort* __restrict__ WcT, ushort* __restrict__ relsB,
        ushort* __restrict__ entEmbB, float* __restrict__ entAtt) {
    __shared__ float tile[32][33];
    int b = blockIdx.x, t = threadIdx.x;
    if (b < 1536) {                    // seqB: plain f32->bf16 cast of seq (4096x768)
        long base = (long)b*2048 + t*8;
        float4 f0 = *(const float4*)(seq + base);
        float4 f1 = *(const float4*)(seq + base + 4);
        ushort o[8] = { f2bf(f0.x), f2bf(f0.y), f2bf(f0.z), f2bf(f0.w),
                        f2bf(f1.x), f2bf(f1.y), f2bf(f1.z), f2bf(f1.w) };
        *(uint4*)(seqB + base) = *(const uint4*)o;
    } else if (b < 3264) {             // WeT: 24 x 72 tiles
        int r = b - 1536;
        tcast32(We, WeT, D3_, D_, r/24, r%24, tile, t);
    } else if (b < 4992) {             // Wq/Wk/Wv: 3 x (24 x 24)
        int r3 = b - 3264;
        int z = r3 / 576, r = r3 % 576;
        const float* X = (z == 0) ? Wq : (z == 1) ? Wk : Wv;
        tcast32(X, W3T + (size_t)z*D_*D_, D_, D_, r/24, r%24, tile, t);
    } else if (b < 5088) {             // WcT: 4 x 24
        int r = b - 4992;
        tcast32(Wc, WcT, D_, R_, r/4, r%4, tile, t);
    } else if (b < 5161) {             // rels cast: 73 blocks x 1024 elems
        int base = (b - 5088) * 1024 + t * 4;
        #pragma unroll
        for (int j = 0; j < 4; j++) {
            int i = base + j;
            if (i < R_*D_) relsB[i] = f2bf(rels[i]);
        }
    } else {
        int b2 = b - 5161;
        if (b2 < 288) {                // ent_emb (logsumexp) -> bf16, N*E*D = 288*256
            int idx = b2*256 + t;
            int d  = idx % D_;
            int ne = idx / D_;
            int e  = ne % E_;
            int n  = ne / E_;
            const int* pp = epos + (n*E_ + e)*M_;
            float v[M_];
            float mx = -1e30f;
            #pragma unroll
            for (int m = 0; m < M_; m++) {
                int pos = pp[m] + 1;  // OFFSET
                v[m] = seq[((long)n*C_ + pos)*D_ + d];
                mx = fmaxf(mx, v[m]);
            }
            float s = 0.f;
            #pragma unroll
            for (int m = 0; m < M_; m++) s += expf(v[m] - mx);
            entEmbB[idx] = f2bf(mx + logf(s));
        } else {                       // ent_att over N*E*H*C = 4608*256
            long idx = (long)(b2 - 288)*256 + t;
            int c = idx % C_;
            long r = idx / C_;
            int h = r % H_; r /= H_;
            int e = r % E_;
            int n = r / E_;
            const int* pp = epos + (n*E_ + e)*M_;
            float s = 0.f;
            #pragma unroll
            for (int m = 0; m < M_; m++) {
                int pos = pp[m] + 1;
                s += att[(((long)n*H_ + h)*C_ + pos)*C_ + c];
            }
            entAtt[idx] = s * (1.0f / M_);
        }
    }
}

// ---------------- ht_att only (gather stage eliminated) ----------------
__global__ __launch_bounds__(256) void k_htatt(
        const float* __restrict__ entAtt, const int* __restrict__ hts,
        ushort* __restrict__ bhtAtt) {
    __shared__ float red[256];
    int np = blockIdx.x, t = threadIdx.x;
    int p = np % P_, n = np / P_;
    int hi = hts[(n*P_ + p)*2 + 0];
    int ti = hts[(n*P_ + p)*2 + 1];
    const float* ha = entAtt + ((long)n*E_ + hi)*H_*C_;
    const float* ta = entAtt + ((long)n*E_ + ti)*H_*C_;
    float vals[C_/256];
    float lsum = 0.f;
    #pragma unroll
    for (int i = 0; i < C_/256; i++) {
        int c = t + i*256;
        float s = 0.f;
        #pragma unroll
        for (int h = 0; h < H_; h++) s += ha[h*C_ + c] * ta[h*C_ + c];
        s *= (1.0f / H_);
        vals[i] = s;
        lsum += s;
    }
    red[t] = lsum; __syncthreads();
    for (int s1 = 128; s1; s1 >>= 1) { if (t < s1) red[t] += red[t+s1]; __syncthreads(); }
    float inv = 1.0f / (red[0] + 1e-5f);
    #pragma unroll
    for (int i = 0; i < C_/256; i++)
        bhtAtt[(long)np*C_ + t + i*256] = f2bf(vals[i] * inv);
}

// ---------------- generic bf16 MFMA GEMM (distance-2 pipeline, counted vmcnt) ----------------
__device__ __forceinline__ void gemm_core(
        int bx, int by,
        const ushort* __restrict__ A, const ushort* __restrict__ Bt,
        const float* __restrict__ bias, float* __restrict__ Cf, ushort* __restrict__ Cb,
        long cfo, long cbo,
        int M, int N, int Npad, int K,
        int lda, int ldb, int ldcf, int ldcb,
        int act, int biasM,
        ushort* __restrict__ As, ushort* __restrict__ Bs) {
    int t = threadIdx.x;
    int m0 = by * 128, n0 = bx * 128;
    int lr = t >> 2;            // 0..63
    int lc = (t & 3) * 8;       // 0,8,16,24
    int wv = t >> 6, lane = t & 63;
    int quad = lane >> 4, lm = lane & 15;
    int wm = (wv >> 1) * 64, wn = (wv & 1) * 64;

    const ushort* pA0 = A + (long)min(m0 + lr,      M-1)*lda + lc;
    const ushort* pA1 = A + (long)min(m0 + lr + 64, M-1)*lda + lc;
    const ushort* pB0 = Bt + (long)min(n0 + lr,      N-1)*ldb + lc;
    const ushort* pB1 = Bt + (long)min(n0 + lr + 64, N-1)*ldb + lc;

    v4f acc[4][4];
    #pragma unroll
    for (int i = 0; i < 4; i++)
        #pragma unroll
        for (int j = 0; j < 4; j++)
            acc[i][j] = (v4f){0.f, 0.f, 0.f, 0.f};

    int nIter = K >> 5;
    gl_lds16(pA0, As + t*8);
    gl_lds16(pA1, As + 2048 + t*8);
    gl_lds16(pB0, Bs + t*8);
    gl_lds16(pB1, Bs + 2048 + t*8);
    if (nIter > 1) {
        gl_lds16(pA0 + 32, As + 4096 + t*8);
        gl_lds16(pA1 + 32, As + 4096 + 2048 + t*8);
        gl_lds16(pB0 + 32, Bs + 4096 + t*8);
        gl_lds16(pB1 + 32, Bs + 4096 + 2048 + t*8);
    }

    #pragma unroll 1
    for (int it = 0; it < nIter; ++it) {
        int cur = (it & 3) * 4096;
        if (it + 2 < nIter) {
            asm volatile("s_waitcnt vmcnt(4)\n\ts_barrier" ::: "memory");
            int nb = ((it + 2) & 3) * 4096;
            int k2 = (it + 2) << 5;
            gl_lds16(pA0 + k2, As + nb + t*8);
            gl_lds16(pA1 + k2, As + nb + 2048 + t*8);
            gl_lds16(pB0 + k2, Bs + nb + t*8);
            gl_lds16(pB1 + k2, Bs + nb + 2048 + t*8);
        } else {
            asm volatile("s_waitcnt vmcnt(0)\n\ts_barrier" ::: "memory");
        }
        v8s a[4], b[4];
        #pragma unroll
        for (int i = 0; i < 4; i++)
            a[i] = *(const v8s*)(As + cur + (wm + i*16 + lm)*32 + quad*8);
        #pragma unroll
        for (int j = 0; j < 4; j++)
            b[j] = *(const v8s*)(Bs + cur + (wn + j*16 + lm)*32 + quad*8);
        #pragma unroll
        for (int i = 0; i < 4; i++)
            #pragma unroll
            for (int j = 0; j < 4; j++)
                acc[i][j] = __builtin_amdgcn_mfma_f32_16x16x32_bf16(a[i], b[j], acc[i][j], 0, 0, 0);
    }

    #pragma unroll
    for (int j = 0; j < 4; j++) {
        int gn = n0 + wn + j*16 + lm;
        if (gn >= Npad) continue;
        bool vld = gn < N;
        float bvn = (bias && !biasM && vld) ? bias[gn] : 0.f;
        #pragma unroll
        for (int i = 0; i < 4; i++) {
            #pragma unroll
            for (int reg = 0; reg < 4; reg++) {
                int gm = m0 + wm + i*16 + quad*4 + reg;
                if (gm >= M) continue;
                float v = 0.f;
                if (vld) {
                    v = acc[i][j][reg] + bvn;
                    if (bias && biasM) v += bias[gm];
                    if (act == 1) v = tanhf(v);
                }
                if (Cf) Cf[cfo + (long)gm*ldcf + gn] = v;
                if (Cb) Cb[cbo + (long)gm*ldcb + gn] = f2bf(v);
            }
        }
    }
}

__global__ __launch_bounds__(256) void k_mfma_bt(
        const ushort* __restrict__ A, const ushort* __restrict__ Bt,
        const float* __restrict__ bias, float* __restrict__ Cf, ushort* __restrict__ Cb,
        int M, int N, int Npad, int K,
        int lda, int ldb, int ldcf, int ldcb, int nb2,
        long sA1, long sA2, long sB1, long sB2,
        long sCf1, long sCf2, long sCb1, long sCb2,
        int act, int biasM) {
    __shared__ ushort As[4][4096];
    __shared__ ushort Bs[4][4096];
    int z = blockIdx.z;
    int b1 = z / nb2, b2 = z % nb2;
    gemm_core(blockIdx.x, blockIdx.y,
              A + b1*sA1 + b2*sA2, Bt + b1*sB1 + b2*sB2, bias, Cf, Cb,
              b1*sCf1 + b2*sCf2, b1*sCb1 + b2*sCb2,
              M, N, Npad, K, lda, ldb, ldcf, ldcb, act, biasM,
              &As[0][0], &Bs[0][0]);
}

// ---------------- fused htr GEMM: tanh(hs@We1 + ts@We2 + htAtt@seqW3 + be) ----------------
// A gathered on the fly: k<768 -> entEmbB[hi]; k<1536 -> entEmbB[ti]; else bhtAtt row.
// B: k<1536 -> WeT rows; else seqW3T rows (batch slice). K = 2560, 80 iters.
__global__ __launch_bounds__(256) void k_htr(
        const ushort* __restrict__ entEmbB, const ushort* __restrict__ bhtAtt,
        const ushort* __restrict__ WeT, const ushort* __restrict__ seqW3T,
        const int* __restrict__ hts, const float* __restrict__ be,
        float* __restrict__ htr, ushort* __restrict__ bhtr) {
    __shared__ ushort As[4][4096];
    __shared__ ushort Bs[4][4096];
    int n = blockIdx.z;
    int m0 = blockIdx.y * 128, n0 = blockIdx.x * 128;
    int t = threadIdx.x;
    int lr = t >> 2, lc = (t & 3) * 8;
    int wv = t >> 6, lane = t & 63;
    int quad = lane >> 4, lm = lane & 15;
    int wm = (wv >> 1) * 64, wn = (wv & 1) * 64;

    const ushort *aH[2], *aT[2], *aP[2], *bW[2], *bS[2];
    #pragma unroll
    for (int r = 0; r < 2; r++) {
        int p = min(m0 + lr + r*64, P_-1);
        int np = n*P_ + p;
        int hi = hts[np*2], ti = hts[np*2 + 1];
        aH[r] = entEmbB + (long)(n*E_ + hi)*D_ + lc;
        aT[r] = entEmbB + (long)(n*E_ + ti)*D_ + lc;
        aP[r] = bhtAtt + (long)np*C_ + lc;
        int dout = min(n0 + lr + r*64, D_-1);
        bW[r] = WeT + (long)dout*D3_ + lc;
        bS[r] = seqW3T + (long)dout*(N_*C_) + n*C_ + lc;
    }

    v4f acc[4][4];
    #pragma unroll
    for (int i = 0; i < 4; i++)
        #pragma unroll
        for (int j = 0; j < 4; j++)
            acc[i][j] = (v4f){0.f, 0.f, 0.f, 0.f};

    const int nIter = 80;   // K = 2560
    auto stage = [&](int it, int buf) {
        int k0 = it << 5;
        const ushort *a0, *a1, *b0, *b1;
        if (k0 < 768)       { a0 = aH[0] + k0;        a1 = aH[1] + k0; }
        else if (k0 < 1536) { a0 = aT[0] + (k0-768);  a1 = aT[1] + (k0-768); }
        else                { a0 = aP[0] + (k0-1536); a1 = aP[1] + (k0-1536); }
        if (k0 < 1536)      { b0 = bW[0] + k0;        b1 = bW[1] + k0; }
        else                { b0 = bS[0] + (k0-1536); b1 = bS[1] + (k0-1536); }
        gl_lds16(a0, &As[buf][t*8]);
        gl_lds16(a1, &As[buf][2048 + t*8]);
        gl_lds16(b0, &Bs[buf][t*8]);
        gl_lds16(b1, &Bs[buf][2048 + t*8]);
    };
    stage(0, 0);
    stage(1, 1);

    #pragma unroll 1
    for (int it = 0; it < nIter; ++it) {
        int cur = it & 3;
        if (it + 2 < nIter) {
            asm volatile("s_waitcnt vmcnt(4)\n\ts_barrier" ::: "memory");
            stage(it + 2, (it + 2) & 3);
        } else {
            asm volatile("s_waitcnt vmcnt(0)\n\ts_barrier" ::: "memory");
        }
        v8s a[4], b[4];
        #pragma unroll
        for (int i = 0; i < 4; i++)
            a[i] = *(const v8s*)(&As[cur][(wm + i*16 + lm)*32 + quad*8]);
        #pragma unroll
        for (int j = 0; j < 4; j++)
            b[j] = *(const v8s*)(&Bs[cur][(wn + j*16 + lm)*32 + quad*8]);
        #pragma unroll
        for (int i = 0; i < 4; i++)
            #pragma unroll
            for (int j = 0; j < 4; j++)
                acc[i][j] = __builtin_amdgcn_mfma_f32_16x16x32_bf16(a[i], b[j], acc[i][j], 0, 0, 0);
    }

    long co = (long)n*P_*D_;
    #pragma unroll
    for (int j = 0; j < 4; j++) {
        int gn = n0 + wn + j*16 + lm;
        float bvn = be[gn];
        #pragma unroll
        for (int i = 0; i < 4; i++) {
            #pragma unroll
            for (int reg = 0; reg < 4; reg++) {
                int gm = m0 + wm + i*16 + quad*4 + reg;
                if (gm >= P_) continue;
                float v = tanhf(acc[i][j][reg] + bvn);
                htr[co + (long)gm*D_ + gn] = v;
                bhtr[co + (long)gm*D_ + gn] = f2bf(v);
            }
        }
    }
}

// fused q/k/v projections in one launch: grid (6, 25)
__global__ __launch_bounds__(256) void k_qkv(
        const ushort* __restrict__ bhtr, const ushort* __restrict__ WqT,
        const ushort* __restrict__ WkT, const ushort* __restrict__ WvT,
        const ushort* __restrict__ relsB,
        const float* __restrict__ bq, const float* __restrict__ bk,
        const float* __restrict__ bv,
        ushort* __restrict__ bqb, ushort* __restrict__ bkb, ushort* __restrict__ vT) {
    __shared__ ushort As[4][4096];
    __shared__ ushort Bs[4][4096];
    int x = blockIdx.x, y = blockIdx.y;
    if (y < 18) {
        gemm_core(x, y, bhtr, WqT, bq, nullptr, bqb, 0, 0,
                  NP_, D_, D_, D_, D_, D_, 0, D_, 0, 0, &As[0][0], &Bs[0][0]);
    } else if (y == 18) {
        gemm_core(x, 0, relsB, WkT, bk, nullptr, bkb, 0, 0,
                  R_, D_, D_, D_, D_, D_, 0, D_, 0, 0, &As[0][0], &Bs[0][0]);
    } else if (x == 0) {
        gemm_core(0, y - 19, WvT, relsB, bv, nullptr, vT, 0, 0,
                  D_, R_, 128, D_, D_, D_, 0, 128, 0, 1, &As[0][0], &Bs[0][0]);
    }
}

// ---------------- fused attn1: scores1 + softmax + P@V, per (m-tile, head) ----------------
__global__ __launch_bounds__(256) void k_attn1f(
        const ushort* __restrict__ qb, const ushort* __restrict__ kb,
        const ushort* __restrict__ vT, ushort* __restrict__ o1b) {
    int mt = blockIdx.x, h = blockIdx.y;
    int m0 = mt * 128;
    __shared__ ushort U[128*128];      // Qs[128*64] | Ks[128*64]; later Ps[128*128]
    __shared__ ushort Vs[64*128];
    __shared__ float rowm[2][128];
    __shared__ float rowl[2][128];
    ushort* Qs = U;
    ushort* Ks = U + 128*64;
    ushort* Ps = U;
    int t = threadIdx.x;
    const uint4 z4 = {0u,0u,0u,0u};
    #pragma unroll
    for (int i = 0; i < 4; i++) {
        int id = t + i*256;            // 0..1023
        int row = id >> 3, c8 = (id & 7) * 8;
        int np = m0 + row;
        uint4 qv = z4;
        if (np < NP_) qv = *(const uint4*)(qb + (long)np*D_ + h*HD_ + c8);
        *(uint4*)(Qs + row*64 + c8) = qv;
        uint4 kv = z4;
        if (row < R_) kv = *(const uint4*)(kb + (long)row*D_ + h*HD_ + c8);
        *(uint4*)(Ks + row*64 + c8) = kv;
    }
    #pragma unroll
    for (int i = 0; i < 4; i++) {
        int id = t + i*256;
        int e = id >> 4, c8 = (id & 15) * 8;
        *(uint4*)(Vs + e*128 + c8) = *(const uint4*)(vT + ((long)h*HD_ + e)*128 + c8);
    }
    __syncthreads();
    int wv = t >> 6, lane = t & 63;
    int quad = lane >> 4, lm = lane & 15;
    int wm = (wv >> 1) * 64, wn = (wv & 1) * 64;
    int side = wv & 1;

    v4f acc[4][4];
    #pragma unroll
    for (int i = 0; i < 4; i++)
        #pragma unroll
        for (int j = 0; j < 4; j++)
            acc[i][j] = (v4f){0.f,0.f,0.f,0.f};
    #pragma unroll
    for (int k0 = 0; k0 < 64; k0 += 32) {
        v8s a[4], b[4];
        #pragma unroll
        for (int i = 0; i < 4; i++) a[i] = *(const v8s*)(Qs + (wm + i*16 + lm)*64 + k0 + quad*8);
        #pragma unroll
        for (int j = 0; j < 4; j++) b[j] = *(const v8s*)(Ks + (wn + j*16 + lm)*64 + k0 + quad*8);
        #pragma unroll
        for (int i = 0; i < 4; i++)
            #pragma unroll
            for (int j = 0; j < 4; j++)
                acc[i][j] = __builtin_amdgcn_mfma_f32_16x16x32_bf16(a[i], b[j], acc[i][j], 0, 0, 0);
    }
    #pragma unroll
    for (int j = 0; j < 4; j++) {
        int col = wn + j*16 + lm;
        bool ok = col < R_;
        #pragma unroll
        for (int i = 0; i < 4; i++)
            #pragma unroll
            for (int reg = 0; reg < 4; reg++)
                acc[i][j][reg] = ok ? acc[i][j][reg]*SCALE_ : -1e30f;
    }
    #pragma unroll
    for (int i = 0; i < 4; i++)
        #pragma unroll
        for (int reg = 0; reg < 4; reg++) {
            float m = fmaxf(fmaxf(acc[i][0][reg], acc[i][1][reg]),
                            fmaxf(acc[i][2][reg], acc[i][3][reg]));
            #pragma unroll
            for (int o = 1; o < 16; o <<= 1) m = fmaxf(m, __shfl_xor(m, o));
            if (lm == 0) rowm[side][wm + i*16 + quad*4 + reg] = m;
        }
    __syncthreads();
    #pragma unroll
    for (int i = 0; i < 4; i++)
        #pragma unroll
        for (int reg = 0; reg < 4; reg++) {
            int r = wm + i*16 + quad*4 + reg;
            float m = fmaxf(rowm[0][r], rowm[1][r]);
            float s = 0.f;
            #pragma unroll
            for (int j = 0; j < 4; j++) {
                float e = expf(acc[i][j][reg] - m);
                acc[i][j][reg] = e;
                s += e;
            }
            #pragma unroll
            for (int o = 1; o < 16; o <<= 1) s += __shfl_xor(s, o);
            if (lm == 0) rowl[side][r] = s;
        }
    __syncthreads();
    #pragma unroll
    for (int i = 0; i < 4; i++)
        #pragma unroll
        for (int reg = 0; reg < 4; reg++) {
            int r = wm + i*16 + quad*4 + reg;
            float inv = 1.0f / (rowl[0][r] + rowl[1][r]);
            #pragma unroll
            for (int j = 0; j < 4; j++)
                Ps[r*128 + wn + j*16 + lm] = f2bf(acc[i][j][reg] * inv);
        }
    __syncthreads();
    v4f acc2[2][4];
    #pragma unroll
    for (int i = 0; i < 2; i++)
        #pragma unroll
        for (int j = 0; j < 4; j++)
            acc2[i][j] = (v4f){0.f,0.f,0.f,0.f};
    int wm2 = wv * 32;
    #pragma unroll
    for (int k0 = 0; k0 < 128; k0 += 32) {
        v8s a2[2], b2[4];
        #pragma unroll
        for (int i = 0; i < 2; i++) a2[i] = *(const v8s*)(Ps + (wm2 + i*16 + lm)*128 + k0 + quad*8);
        #pragma unroll
        for (int j = 0; j < 4; j++) b2[j] = *(const v8s*)(Vs + (j*16 + lm)*128 + k0 + quad*8);
        #pragma unroll
        for (int i = 0; i < 2; i++)
            #pragma unroll
            for (int j = 0; j < 4; j++)
                acc2[i][j] = __builtin_amdgcn_mfma_f32_16x16x32_bf16(a2[i], b2[j], acc2[i][j], 0, 0, 0);
    }
    #pragma unroll
    for (int i = 0; i < 2; i++)
        #pragma unroll
        for (int j = 0; j < 4; j++)
            #pragma unroll
            for (int reg = 0; reg < 4; reg++) {
                int row = m0 + wm2 + i*16 + quad*4 + reg;
                if (row >= NP_) continue;
                o1b[(long)row*D_ + h*HD_ + j*16 + lm] = f2bf(acc2[i][j][reg]);
            }
}

// ---------------- fused attn2 (flash-style) + tanh epilogue ----------------
__global__ __launch_bounds__(256) void k_attn2f(
        const ushort* __restrict__ o1b, float* __restrict__ o2) {
    int qt = blockIdx.x;
    int zz = blockIdx.y;
    int n = zz / H_, h = zz % H_;
    int q0 = qt * 128;
    __shared__ ushort Qs[128*64];
    __shared__ ushort KV[128*64];
    __shared__ ushort Ps[128*128];
    __shared__ float rowm[2][128], rowl[2][128];
    __shared__ float mrun[128], lrun[128], alphaS[128];
    int t = threadIdx.x;
    const ushort* base = o1b + (long)n*P_*D_ + h*HD_;
    const uint4 z4 = {0u,0u,0u,0u};
    #pragma unroll
    for (int i = 0; i < 4; i++) {
        int id = t + i*256;
        int row = id >> 3, c8 = (id & 7) * 8;
        int q = q0 + row;
        uint4 v = z4;
        if (q < P_) v = *(const uint4*)(base + (long)q*D_ + c8);
        *(uint4*)(Qs + row*64 + c8) = v;
    }
    if (t < 128) { mrun[t] = -1e30f; lrun[t] = 0.f; }
    __syncthreads();
    int wv = t >> 6, lane = t & 63;
    int quad = lane >> 4, lm = lane & 15;
    int wm = (wv >> 1) * 64, wn = (wv & 1) * 64;
    int side = wv & 1;
    int wm2 = wv * 32;
    v4f acc2[2][4];
    #pragma unroll
    for (int i = 0; i < 2; i++)
        #pragma unroll
        for (int j = 0; j < 4; j++)
            acc2[i][j] = (v4f){0.f,0.f,0.f,0.f};

    #pragma unroll 1
    for (int c = 0; c < 5; c++) {
        #pragma unroll
        for (int i = 0; i < 4; i++) {
            int id = t + i*256;
            int row = id >> 3, c8 = (id & 7) * 8;
            int q = c*128 + row;
            uint4 v = z4;
            if (q < P_) v = *(const uint4*)(base + (long)q*D_ + c8);
            *(uint4*)(KV + row*64 + c8) = v;
        }
        __syncthreads();
        v4f acc[4][4];
        #pragma unroll
        for (int i = 0; i < 4; i++)
            #pragma unroll
            for (int j = 0; j < 4; j++)
                acc[i][j] = (v4f){0.f,0.f,0.f,0.f};
        #pragma unroll
        for (int k0 = 0; k0 < 64; k0 += 32) {
            v8s a[4], b[4];
            #pragma unroll
            for (int i = 0; i < 4; i++) a[i] = *(const v8s*)(Qs + (wm + i*16 + lm)*64 + k0 + quad*8);
            #pragma unroll
            for (int j = 0; j < 4; j++) b[j] = *(const v8s*)(KV + (wn + j*16 + lm)*64 + k0 + quad*8);
            #pragma unroll
            for (int i = 0; i < 4; i++)
                #pragma unroll
                for (int j = 0; j < 4; j++)
                    acc[i][j] = __builtin_amdgcn_mfma_f32_16x16x32_bf16(a[i], b[j], acc[i][j], 0, 0, 0);
        }
        #pragma unroll
        for (int j = 0; j < 4; j++) {
            int col = c*128 + wn + j*16 + lm;
            bool ok = col < P_;
            #pragma unroll
            for (int i = 0; i < 4; i++)
                #pragma unroll
                for (int reg = 0; reg < 4; reg++)
                    acc[i][j][reg] = ok ? acc[i][j][reg]*SCALE_ : -1e30f;
        }
        #pragma unroll
        for (int i = 0; i < 4; i++)
            #pragma unroll
            for (int reg = 0; reg < 4; reg++) {
                float m = fmaxf(fmaxf(acc[i][0][reg], acc[i][1][reg]),
                                fmaxf(acc[i][2][reg], acc[i][3][reg]));
                #pragma unroll
                for (int o = 1; o < 16; o <<= 1) m = fmaxf(m, __shfl_xor(m, o));
                if (lm == 0) rowm[side][wm + i*16 + quad*4 + reg] = m;
            }
        __syncthreads();
        #pragma unroll
        for (int i = 0; i < 4; i++)
            #pragma unroll
            for (int reg = 0; reg < 4; reg++) {
                int r = wm + i*16 + quad*4 + reg;
                float mc = fmaxf(rowm[0][r], rowm[1][r]);
                float mn = fmaxf(mrun[r], mc);
                float s = 0.f;
                #pragma unroll
                for (int j = 0; j < 4; j++) {
                    float e = expf(acc[i][j][reg] - mn);
                    acc[i][j][reg] = e;
                    s += e;
                }
                #pragma unroll
                for (int o = 1; o < 16; o <<= 1) s += __shfl_xor(s, o);
                if (lm == 0) rowl[side][r] = s;
            }
        __syncthreads();
        if (t < 128) {
            float mo = mrun[t];
            float mc = fmaxf(rowm[0][t], rowm[1][t]);
            float mn = fmaxf(mo, mc);
            float al = expf(mo - mn);
            lrun[t] = lrun[t]*al + rowl[0][t] + rowl[1][t];
            mrun[t] = mn;
            alphaS[t] = al;
        }
        // stage V^T for this chunk via LDS transpose
        #pragma unroll
        for (int i = 0; i < 4; i++) {
            int id = t + i*256;
            int q = id & 127, e0 = (id >> 7) * 8;
            int gq = c*128 + q;
            uint4 v = z4;
            if (gq < P_) v = *(const uint4*)(base + (long)gq*D_ + e0);
            const ushort* pv = (const ushort*)&v;
            #pragma unroll
            for (int j = 0; j < 8; j++) KV[(e0+j)*128 + q] = pv[j];
        }
        #pragma unroll
        for (int i = 0; i < 4; i++)
            #pragma unroll
            for (int reg = 0; reg < 4; reg++) {
                int r = wm + i*16 + quad*4 + reg;
                #pragma unroll
                for (int j = 0; j < 4; j++)
                    Ps[r*128 + wn + j*16 + lm] = f2bf(acc[i][j][reg]);
            }
        __syncthreads();
        #pragma unroll
        for (int i = 0; i < 2; i++) {
            #pragma unroll
            for (int reg = 0; reg < 4; reg++) {
                float al = alphaS[wm2 + i*16 + quad*4 + reg];
                #pragma unroll
                for (int j = 0; j < 4; j++)
                    acc2[i][j][reg] *= al;
            }
        }
        #pragma unroll
        for (int k0 = 0; k0 < 128; k0 += 32) {
            v8s a2[2], b2[4];
            #pragma unroll
            for (int i = 0; i < 2; i++) a2[i] = *(const v8s*)(Ps + (wm2 + i*16 + lm)*128 + k0 + quad*8);
            #pragma unroll
            for (int j = 0; j < 4; j++) b2[j] = *(const v8s*)(KV + (j*16 + lm)*128 + k0 + quad*8);
            #pragma unroll
            for (int i = 0; i < 2; i++)
                #pragma unroll
                for (int j = 0; j < 4; j++)
                    acc2[i][j] = __builtin_amdgcn_mfma_f32_16x16x32_bf16(a2[i], b2[j], acc2[i][j], 0, 0, 0);
        }
        __syncthreads();
    }
    #pragma unroll
    for (int i = 0; i < 2; i++)
        #pragma unroll
        for (int j = 0; j < 4; j++)
            #pragma unroll
            for (int reg = 0; reg < 4; reg++) {
                int row = wm2 + i*16 + quad*4 + reg;
                int q = q0 + row;
                if (q >= P_) continue;
                float l = lrun[row];
                o2[((long)n*P_ + q)*D_ + h*HD_ + j*16 + lm] = tanhf(acc2[i][j][reg] / l);
            }
}

// ---------------- x = LN(htr + o2_tanh) -> bf16 ----------------
__global__ void k_ln(const float* __restrict__ htr, const float* __restrict__ o2,
                     const float* __restrict__ g, const float* __restrict__ b,
                     ushort* __restrict__ bx) {
    int np = blockIdx.x;
    int t = threadIdx.x;
    __shared__ float red[256];
    float v[D_/256];
    float s = 0.f;
    #pragma unroll
    for (int i = 0; i < D_/256; i++) {
        int d = t + i*256;
        float val = htr[(long)np*D_ + d] + o2[(long)np*D_ + d];
        v[i] = val; s += val;
    }
    red[t] = s; __syncthreads();
    for (int s1 = 128; s1; s1 >>= 1) { if (t < s1) red[t] += red[t+s1]; __syncthreads(); }
    float mu = red[0] * (1.0f/D_);
    __syncthreads();
    float s2 = 0.f;
    #pragma unroll
    for (int i = 0; i < D_/256; i++) { float dx = v[i]-mu; s2 += dx*dx; }
    red[t] = s2; __syncthreads();
    for (int s1 = 128; s1; s1 >>= 1) { if (t < s1) red[t] += red[t+s1]; __syncthreads(); }
    float inv = rsqrtf(red[0]*(1.0f/D_) + 1e-5f);
    #pragma unroll
    for (int i = 0; i < D_/256; i++) {
        int d = t + i*256;
        bx[(long)np*D_ + d] = f2bf((v[i]-mu)*inv*g[d] + b[d]);
    }
}

extern "C" void kernel_launch(void* const* d_in, const int* in_sizes, int n_in,
                              void* d_out, int out_size, void* d_ws, size_t ws_size,
                              hipStream_t stream) {
    const float* seq   = (const float*)d_in[0];
    const float* att   = (const float*)d_in[1];
    const int*   epos  = (const int*)d_in[2];
    const int*   hts   = (const int*)d_in[3];
    const float* rels  = (const float*)d_in[4];
    const float* We    = (const float*)d_in[5];
    const float* be    = (const float*)d_in[6];
    const float* Wq    = (const float*)d_in[7];
    const float* bq    = (const float*)d_in[8];
    const float* Wk    = (const float*)d_in[9];
    const float* bk    = (const float*)d_in[10];
    const float* Wv    = (const float*)d_in[11];
    const float* bv    = (const float*)d_in[12];
    const float* ln_g  = (const float*)d_in[13];
    const float* ln_b  = (const float*)d_in[14];
    const float* Wc    = (const float*)d_in[15];
    const float* bc    = (const float*)d_in[16];
    float* out = (float*)d_out;
    float* w = (float*)d_ws;

    // ---- f32 workspace ----
    float* entAtt  = w;                                 // N*E*H*C
    float* htr     = entAtt + (size_t)N_*E_*H_*C_;      // NP*D
    float* o2      = htr    + (size_t)NP_*D_;           // NP*D
    // ---- bf16 workspace ----
    ushort* entEmbB = (ushort*)(o2 + (size_t)NP_*D_);   // N*E*D
    ushort* bhtAtt = entEmbB + (size_t)N_*E_*D_;        // NP*C
    ushort* seqB   = bhtAtt + (size_t)NP_*C_;           // N*C*D (4096x768)
    ushort* seqW3T = seqB  + (size_t)N_*C_*D_;          // D x (N*C) (768x4096)
    ushort* WeT    = seqW3T + (size_t)D_*N_*C_;         // 768 x 2304
    ushort* WqT    = WeT   + (size_t)D_*D3_;            // W3T base
    ushort* WkT    = WqT   + (size_t)D_*D_;
    ushort* WvT    = WkT   + (size_t)D_*D_;
    ushort* WcT    = WvT   + (size_t)D_*D_;
    ushort* relsB  = WcT   + (size_t)D_*R_;
    ushort* bhtr   = relsB + (size_t)R_*D_;             // NP*D
    ushort* bqb    = bhtr  + (size_t)NP_*D_;            // NP*D
    ushort* bkb    = bqb   + (size_t)NP_*D_;            // R*D
    ushort* vT     = bkb   + (size_t)R_*D_;             // 768 x 128
    ushort* o1b    = vT    + (size_t)D_*128;            // NP*D
    ushort* bxb    = o1b   + (size_t)NP_*D_;            // NP*D

    // L1: casts + transposes + ent_emb(bf16) + ent_att
    k_prep_ent<<<10057, 256, 0, stream>>>(seq, att, epos, We, Wq, Wk, Wv, Wc, rels,
                                          seqB, WeT, WqT, WcT, relsB, entEmbB, entAtt);

    // L2: ht_att (2208 blocks, high occupancy)
    k_htatt<<<NP_, 256, 0, stream>>>(entAtt, hts, bhtAtt);

    // L3: seqW3T = We3^T @ seq^T  (M=768, N=4096, K=768) -> bf16 [768 x 4096]
    k_mfma_bt<<<dim3(32, 6, 1), 256, 0, stream>>>(
        WeT + 1536, seqB, nullptr, nullptr, seqW3T,
        D_, N_*C_, N_*C_, D_, D3_, D_, 0, N_*C_, 1,
        0, 0, 0, 0, 0, 0, 0, 0, 0, 0);

    // L4: htr = tanh(hs@We1 + ts@We2 + htAtt@seqW3 + be)  (fused gather-GEMM, K=2560)
    k_htr<<<dim3(6, 5, N_), 256, 0, stream>>>(
        entEmbB, bhtAtt, WeT, seqW3T, hts, be, htr, bhtr);

    // L5: fused q/k/v projections
    k_qkv<<<dim3(6, 25, 1), 256, 0, stream>>>(
        bhtr, WqT, WkT, WvT, relsB, bq, bk, bv, bqb, bkb, vT);

    // L6: fused attn1 -> o1b
    k_attn1f<<<dim3(18, 12), 256, 0, stream>>>(bqb, bkb, vT, o1b);

    // L7: fused attn2 (flash) -> o2 (tanh applied)
    k_attn2f<<<dim3(5, 48), 256, 0, stream>>>(o1b, o2);

    // L8: x = LN(htr + o2) -> bf16
    k_ln<<<NP_, 256, 0, stream>>>(htr, o2, ln_g, ln_b, bxb);

    // L9: logits = bxb @ WcT^T + bc -> f32 out
    k_mfma_bt<<<dim3(1, 18, 1), 256, 0, stream>>>(
        bxb, WcT, bc, out, nullptr,
        NP_, R_, R_, D_, D_, D_, R_, 0, 1,
        0, 0, 0, 0, 0, 0, 0, 0, 0, 0);
}